// Round 19
// baseline (241.820 us; speedup 1.0000x reference)
//
#include <hip/hip_runtime.h>

#define DEV static __device__ __forceinline__

typedef __attribute__((ext_vector_type(8))) short bf16x8;
typedef __attribute__((ext_vector_type(4))) short short4v;
typedef __attribute__((ext_vector_type(4))) float f32x4;

DEV f32x4 mfma16(bf16x8 a, bf16x8 b, f32x4 c){
  return __builtin_amdgcn_mfma_f32_16x16x32_bf16(a, b, c, 0, 0, 0);
}
DEV float bf2f(short s){ union{unsigned u; float f;} v; v.u=((unsigned)(unsigned short)s)<<16; return v.f; }
DEV short f2bf(float f){ union{float f; unsigned u;} v; v.f=f; unsigned r=v.u+0x7fffu+((v.u>>16)&1u); return (short)(r>>16); }
DEV void gload16(const void* g, void* l){
  __builtin_amdgcn_global_load_lds((const __attribute__((address_space(1))) void*)g,
                                   (__attribute__((address_space(3))) void*)l, 16, 0, 0);
}
DEV int cvtpk(float lo, float hi){
  int r; asm("v_cvt_pk_bf16_f32 %0, %1, %2" : "=v"(r) : "v"(lo), "v"(hi)); return r;
}

// ---------------- FAT D: convert wq..wo (2304) || rmsnorm1 (1024) ----------------
__global__ void k_fatD(const float* __restrict__ p0, const float* __restrict__ p1,
                       const float* __restrict__ p2, const float* __restrict__ p3,
                       short* __restrict__ dst,
                       const float* __restrict__ x, const float* __restrict__ g,
                       short* __restrict__ out){
  const int id = blockIdx.x;
  const int tid = threadIdx.x;
  if (id < 2304){
    int v = id*256 + tid;
    const float* src; int rel;
    if      (v < 147456){ src=p0; rel=v; }
    else if (v < 294912){ src=p1; rel=v-147456; }
    else if (v < 442368){ src=p2; rel=v-294912; }
    else                { src=p3; rel=v-442368; }
    float4 xv = ((const float4*)src)[rel];
    short4v o; o.x=f2bf(xv.x); o.y=f2bf(xv.y); o.z=f2bf(xv.z); o.w=f2bf(xv.w);
    ((short4v*)dst)[v] = o;
  } else {
    int row = (id-2304)*4 + (tid>>6);
    int lane = tid & 63;
    const float* xr = x + (size_t)row*768;
    float4 v[3];
    float ss = 0.f;
    #pragma unroll
    for (int i=0;i<3;i++){
      v[i] = *(const float4*)(xr + i*256 + lane*4);
      ss += v[i].x*v[i].x + v[i].y*v[i].y + v[i].z*v[i].z + v[i].w*v[i].w;
    }
    #pragma unroll
    for (int d=32; d>0; d>>=1) ss += __shfl_xor(ss, d);
    float sc = rsqrtf(ss*(1.f/768.f) + 1.1920929e-7f);
    #pragma unroll
    for (int i=0;i<3;i++){
      int c0 = i*256 + lane*4;
      float4 gv = *(const float4*)(g + c0);
      short4v o;
      o.x = f2bf(v[i].x*sc*gv.x); o.y = f2bf(v[i].y*sc*gv.y);
      o.z = f2bf(v[i].z*sc*gv.z); o.w = f2bf(v[i].w*sc*gv.w);
      *(short4v*)(out + (size_t)row*768 + c0) = o;
    }
  }
}

// ---------------- Pipelined QKV GEMM: BM=256, BN=64 (one head/block), K=768 ----------------
// 4 waves; wave = 64 rows x 64 cols (acc[4][4]). Triple-buffered 60KB, counted vmcnt(5),
// single barrier/tile. Epilogue: Q (rope*0.125*log2e), K (rope), V (V^T packed stores).
__launch_bounds__(256, 2)
__global__ void k_qkv(const short* __restrict__ xn, const short* __restrict__ Wqkv,
                      const float* __restrict__ bq, const float* __restrict__ bk,
                      const float* __restrict__ bv,
                      short* __restrict__ Oq, short* __restrict__ Ok, short* __restrict__ Ov){
  __shared__ short lds[3*10240];   // per buf: A [0,8192) = 256x32, B [8192,10240) = 64x32
  const int tid = threadIdx.x;
  const int wave = tid>>6, lane = tid&63;
  const int l15 = lane&15, l4 = lane>>4;
  const int nt = 24;

  const int bid0 = blockIdx.y*36 + blockIdx.x;   // grid (36,16) = 576
  const int bid = (bid0 & 7)*72 + (bid0>>3);
  const int bm = bid / 36, bn = bid % 36;

  const int srcC = ((lane&3) ^ ((lane>>3)&3)) * 8;

  // 5 staging slots per wave: s = wave + 4*i. s<16 -> A rows s*16+..; s>=16 -> B rows (s-16)*16+..
  const short* sSrc[5];
  int sDst[5];
  #pragma unroll
  for (int i=0;i<5;i++){
    int s = wave + 4*i;
    if (s < 16){
      int row = bm*256 + s*16 + (lane>>2);
      sSrc[i] = xn + (size_t)row*768 + srcC;
      sDst[i] = s*512;
    } else {
      int row = bn*64 + (s-16)*16 + (lane>>2);
      sSrc[i] = Wqkv + (size_t)row*768 + srcC;
      sDst[i] = 8192 + (s-16)*512;
    }
  }

  int offA[4], offB[4];
  #pragma unroll
  for (int m=0;m<4;m++){
    int r = wave*64 + m*16 + l15;
    offA[m] = r*32 + ((l4 ^ ((l15>>1)&3))<<3);
  }
  #pragma unroll
  for (int n=0;n<4;n++){
    int r = n*16 + l15;
    offB[n] = 8192 + r*32 + ((l4 ^ ((l15>>1)&3))<<3);
  }

  f32x4 acc[4][4] = {};
  short *b0 = lds, *b1 = lds + 10240, *b2 = lds + 20480;

  #define QSTAGE(buf, t) do{ \
    gload16(sSrc[0] + (size_t)(t)*32, (buf) + sDst[0]); \
    gload16(sSrc[1] + (size_t)(t)*32, (buf) + sDst[1]); \
    gload16(sSrc[2] + (size_t)(t)*32, (buf) + sDst[2]); \
    gload16(sSrc[3] + (size_t)(t)*32, (buf) + sDst[3]); \
    gload16(sSrc[4] + (size_t)(t)*32, (buf) + sDst[4]); \
  }while(0)

  QSTAGE(b0, 0);
  QSTAGE(b1, 1);

  for (int t = 0; t < nt; ++t){
    if (t < nt-1){
      asm volatile("s_waitcnt vmcnt(5)" ::: "memory");
    } else {
      asm volatile("s_waitcnt vmcnt(0)" ::: "memory");
    }
    __builtin_amdgcn_sched_barrier(0);
    __builtin_amdgcn_s_barrier();
    __builtin_amdgcn_sched_barrier(0);

    if (t + 2 < nt) QSTAGE(b2, t+2);

    bf16x8 a0 = *(const bf16x8*)(b0 + offA[0]);
    bf16x8 a1 = *(const bf16x8*)(b0 + offA[1]);
    bf16x8 a2 = *(const bf16x8*)(b0 + offA[2]);
    bf16x8 a3 = *(const bf16x8*)(b0 + offA[3]);
    bf16x8 w0 = *(const bf16x8*)(b0 + offB[0]);
    bf16x8 w1 = *(const bf16x8*)(b0 + offB[1]);
    bf16x8 w2 = *(const bf16x8*)(b0 + offB[2]);
    bf16x8 w3 = *(const bf16x8*)(b0 + offB[3]);

    __builtin_amdgcn_s_setprio(1);
    acc[0][0] = mfma16(a0, w0, acc[0][0]);  acc[0][1] = mfma16(a0, w1, acc[0][1]);
    acc[1][0] = mfma16(a1, w0, acc[1][0]);  acc[1][1] = mfma16(a1, w1, acc[1][1]);
    acc[2][0] = mfma16(a2, w0, acc[2][0]);  acc[2][1] = mfma16(a2, w1, acc[2][1]);
    acc[3][0] = mfma16(a3, w0, acc[3][0]);  acc[3][1] = mfma16(a3, w1, acc[3][1]);
    acc[0][2] = mfma16(a0, w2, acc[0][2]);  acc[0][3] = mfma16(a0, w3, acc[0][3]);
    acc[1][2] = mfma16(a1, w2, acc[1][2]);  acc[1][3] = mfma16(a1, w3, acc[1][3]);
    acc[2][2] = mfma16(a2, w2, acc[2][2]);  acc[2][3] = mfma16(a2, w3, acc[2][3]);
    acc[3][2] = mfma16(a3, w2, acc[3][2]);  acc[3][3] = mfma16(a3, w3, acc[3][3]);
    __builtin_amdgcn_s_setprio(0);

    short* tmp = b0; b0 = b1; b1 = b2; b2 = tmp;
  }
  #undef QSTAGE

  const int row0 = bm*256 + wave*64;
  const int proj = bn / 12;
  const int h = bn % 12;
  const float* bs = proj==0 ? bq : (proj==1 ? bk : bv);
  float bvv[4];
  #pragma unroll
  for (int n=0;n<4;n++) bvv[n] = bs[h*64 + n*16 + l15];

  if (proj == 2){
    // V^T [B,H,64,S], packed 8B stores (j=0..3 consecutive in s)
    #pragma unroll
    for (int m=0;m<4;m++){
      int s0 = row0 + m*16 + l4*4;
      int b = s0 >> 11, s = s0 & 2047;
      size_t hb = (size_t)(b*12 + h)*64;
      #pragma unroll
      for (int n=0;n<4;n++){
        short4v pk;
        pk.x = f2bf(acc[m][n][0] + bvv[n]);
        pk.y = f2bf(acc[m][n][1] + bvv[n]);
        pk.z = f2bf(acc[m][n][2] + bvv[n]);
        pk.w = f2bf(acc[m][n][3] + bvv[n]);
        *(short4v*)(Ov + (hb + n*16 + l15)*2048 + s) = pk;
      }
    }
  } else {
    short* O = proj==0 ? Oq : Ok;
    const float sc = proj==0 ? 0.18033688011112042f : 1.0f;   // 0.125*log2(e)
    const float RC = 0.41524101186092034f;  // log2(10000)/32
    float invf0 = exp2f(-(float)l15 * RC);
    float invf1 = exp2f(-(float)(16 + l15) * RC);
    #pragma unroll
    for (int m=0;m<4;m++){
      #pragma unroll
      for (int j=0;j<4;j++){
        int row = row0 + m*16 + l4*4 + j;
        int b = row >> 11, s = row & 2047;
        size_t obase = ((size_t)(b*12 + h)*2048 + (size_t)s)*64;
        float a0 = acc[m][0][j] + bvv[0];
        float a1 = acc[m][1][j] + bvv[1];
        float a2 = acc[m][2][j] + bvv[2];
        float a3 = acc[m][3][j] + bvv[3];
        float sn0, cs0, sn1, cs1;
        __sincosf((float)s * invf0, &sn0, &cs0);
        __sincosf((float)s * invf1, &sn1, &cs1);
        O[obase + l15]      = f2bf((a0*cs0 - a2*sn0)*sc);
        O[obase + 16 + l15] = f2bf((a1*cs1 - a3*sn1)*sc);
        O[obase + 32 + l15] = f2bf((a2*cs0 + a0*sn0)*sc);
        O[obase + 48 + l15] = f2bf((a3*cs1 + a1*sn1)*sc);
      }
    }
  }
}

// ---------------- FAT A (R17 version): attn(768) + convert(20736) + convertT(2304) ----------------
__launch_bounds__(256, 5)
__global__ void k_fatA(const short* __restrict__ Q, const short* __restrict__ Kb,
                       const short* __restrict__ Vb, short* __restrict__ ctx,
                       const float* __restrict__ winf, const float* __restrict__ wgf,
                       const float* __restrict__ wfc2f, short* __restrict__ dstbig,
                       const float* __restrict__ wfc1, short* __restrict__ wfc1T){
  __shared__ short shm[16384];   // attn: K dbuf [0,8192), V dbuf [8192,16384)
  const int id = blockIdx.x;
  const int tid = threadIdx.x;

  if (id < 768){
    const int wave = tid>>6, lane = tid&63;
    const int l15 = lane&15, l4 = lane>>4;
    const int qt = id & 31, bh = id >> 5;
    const short* Qh  = Q  + (size_t)bh*2048*64;
    const short* Kh  = Kb + (size_t)bh*2048*64;
    const short* Vth = Vb + (size_t)bh*64*2048;

    const int r7  = lane>>3;
    const int swz = ((lane&7) ^ r7) << 3;
    const int rr0 = wave*8 + r7, rr1 = 32 + wave*8 + r7;
    const size_t kOff0 = (size_t)rr0*64   + swz, kOff1 = (size_t)rr1*64   + swz;
    const size_t vOff0 = (size_t)rr0*2048 + swz, vOff1 = (size_t)rr1*2048 + swz;

    bf16x8 qf[2];
    #pragma unroll
    for (int kf=0;kf<2;kf++)
      qf[kf] = *(const bf16x8*)(Qh + (size_t)(qt*64 + wave*16 + l15)*64 + kf*32 + l4*8);

    f32x4 cacc[4] = {};
    f32x4 lacc = {};
    union { int w[4]; bf16x8 v; } onesf;
    onesf.w[0] = onesf.w[1] = onesf.w[2] = onesf.w[3] = 0x3F803F80;

    #define STAGE(sel, kv0) do { \
      const short* ksp = Kh + (size_t)(kv0)*64; \
      const short* vsp = Vth + (kv0); \
      short* kd = shm + (sel)*4096 + wave*512; \
      short* vd = shm + 8192 + (sel)*4096 + wave*512; \
      gload16(ksp + kOff0, kd); \
      gload16(ksp + kOff1, kd + 2048); \
      gload16(vsp + vOff0, vd); \
      gload16(vsp + vOff1, vd + 2048); \
    } while(0)

    STAGE(0, 0);

    for (int tt = 0; tt < 32; ++tt){
      const int cur = tt & 1;
      if (tt < 31){
        STAGE(cur^1, (tt+1)*64);
        asm volatile("s_waitcnt vmcnt(4)" ::: "memory");
      } else {
        asm volatile("s_waitcnt vmcnt(0)" ::: "memory");
      }
      __builtin_amdgcn_sched_barrier(0);
      __builtin_amdgcn_s_barrier();
      __builtin_amdgcn_sched_barrier(0);

      const short* KtC = shm + cur*4096;
      const short* VtC = shm + 8192 + cur*4096;

      f32x4 sacc[4] = {};
      __builtin_amdgcn_s_setprio(1);
      #pragma unroll
      for (int kf=0;kf<2;kf++){
        #pragma unroll
        for (int mk=0;mk<4;mk++){
          int r = mk*16 + l15;
          bf16x8 kfr = *(const bf16x8*)(KtC + r*64 + (((kf*4+l4) ^ (l15&7))<<3));
          sacc[mk] = mfma16(kfr, qf[kf], sacc[mk]);
        }
      }
      __builtin_amdgcn_s_setprio(0);

      int pk01[4], pk23[4];
      #pragma unroll
      for (int mk=0;mk<4;mk++){
        float p0 = exp2f(sacc[mk][0]);
        float p1 = exp2f(sacc[mk][1]);
        float p2 = exp2f(sacc[mk][2]);
        float p3 = exp2f(sacc[mk][3]);
        pk01[mk] = cvtpk(p0, p1);
        pk23[mk] = cvtpk(p2, p3);
      }

      #pragma unroll
      for (int ks=0;ks<2;ks++){
        int srcA = l15 + ((l4&1)<<5);
        int srcB = srcA + 16;
        int hi = l4>>1;
        int w0a = __shfl(pk01[2*ks], srcA), w0b = __shfl(pk01[2*ks+1], srcA);
        int w1a = __shfl(pk23[2*ks], srcA), w1b = __shfl(pk23[2*ks+1], srcA);
        int w2a = __shfl(pk01[2*ks], srcB), w2b = __shfl(pk01[2*ks+1], srcB);
        int w3a = __shfl(pk23[2*ks], srcB), w3b = __shfl(pk23[2*ks+1], srcB);
        union { int w[4]; bf16x8 v; } pa;
        pa.w[0] = hi ? w0b : w0a;
        pa.w[1] = hi ? w1b : w1a;
        pa.w[2] = hi ? w2b : w2a;
        pa.w[3] = hi ? w3b : w3a;
        __builtin_amdgcn_s_setprio(1);
        #pragma unroll
        for (int nf=0;nf<4;nf++){
          int dh = nf*16 + l15;
          bf16x8 vf = *(const bf16x8*)(VtC + dh*64 + (((ks*4+l4) ^ (dh&7))<<3));
          cacc[nf] = mfma16(pa.v, vf, cacc[nf]);
        }
        lacc = mfma16(pa.v, onesf.v, lacc);
        __builtin_amdgcn_s_setprio(0);
      }

      __builtin_amdgcn_sched_barrier(0);
      __builtin_amdgcn_s_barrier();
    }
    #undef STAGE

    const int b = bh/12, h = bh%12;
    #pragma unroll
    for (int j=0;j<4;j++){
      float inv = 1.f / lacc[j];
      int s = qt*64 + wave*16 + l4*4 + j;
      size_t base = ((size_t)b*2048 + s)*768 + h*64;
      #pragma unroll
      for (int nf=0;nf<4;nf++)
        ctx[base + nf*16 + l15] = f2bf(cacc[nf][j] * inv);
    }
  } else if (id < 21504){
    int v = (id - 768)*256 + tid;
    const float* src; int rel;
    if      (v < 2359296){ src=winf;  rel=v; }
    else if (v < 4718592){ src=wgf;   rel=v-2359296; }
    else                 { src=wfc2f; rel=v-4718592; }
    float4 x = ((const float4*)src)[rel];
    short4v o; o.x=f2bf(x.x); o.y=f2bf(x.y); o.z=f2bf(x.z); o.w=f2bf(x.w);
    ((short4v*)dstbig)[v] = o;
  } else {
    int idx = id - 21504;
    int f0 = (idx % 96)*32, d0 = (idx / 96)*32;
    float* lt = (float*)shm;     // [32][33]
    int r = tid >> 3, c4 = tid & 7;
    float4 v = *(const float4*)(wfc1 + (size_t)(f0 + r)*768 + d0 + c4*4);
    lt[r*33 + c4*4+0] = v.x; lt[r*33 + c4*4+1] = v.y;
    lt[r*33 + c4*4+2] = v.z; lt[r*33 + c4*4+3] = v.w;
    __syncthreads();
    short4v o;
    o.x = f2bf(lt[(c4*4+0)*33 + r]);
    o.y = f2bf(lt[(c4*4+1)*33 + r]);
    o.z = f2bf(lt[(c4*4+2)*33 + r]);
    o.w = f2bf(lt[(c4*4+3)*33 + r]);
    *(short4v*)(wfc1T + (size_t)(d0 + r)*3072 + f0 + c4*4) = o;
  }
}

// ---------------- FAT B: Wo-RESID(192) + wpart(576) + gemv(1536) ----------------
__launch_bounds__(256, 2)
__global__ void k_fatB(const short* __restrict__ ctxb, const short* __restrict__ wo_b,
                       float* __restrict__ resid, const float* __restrict__ bo,
                       const float* __restrict__ srcf,
                       const short* __restrict__ win_b, const short* __restrict__ wfc1T,
                       short* __restrict__ Pw,
                       const float* __restrict__ bfc1, float* __restrict__ bvg){
  __shared__ short shm[8192];
  const int id = blockIdx.x;
  const int t = threadIdx.x;
  const int wave = t >> 6, lane = t & 63;
  const int l15 = lane & 15, l4 = lane >> 4;
  const int wr = wave >> 1, wc = wave & 1;
  short* lA = shm + wave*1024;
  short* lB = shm + 4096 + wave*1024;

  if (id < 192){
    const int bid = (id & 7)*24 + (id >> 3);
    const int bm = bid / 6, bn = bid % 6;
    f32x4 acc[4][4] = {};
    const short* Ag = ctxb + (size_t)(bm*128 + wave*32 + (lane>>2))*768 + (lane&3)*8;
    const short* Bg = wo_b + (size_t)(bn*128 + wave*32 + (lane>>2))*768 + (lane&3)*8;
    for (int k0 = 0; k0 < 768; k0 += 32){
      __syncthreads();
      gload16(Ag + k0,          lA);
      gload16(Ag + k0 + 16*768, lA + 512);
      gload16(Bg + k0,          lB);
      gload16(Bg + k0 + 16*768, lB + 512);
      __syncthreads();
      bf16x8 af[4], bfr[4];
      #pragma unroll
      for (int m=0;m<4;m++) af[m]  = *(const bf16x8*)(shm + (wr*64 + m*16 + l15)*32 + l4*8);
      #pragma unroll
      for (int n=0;n<4;n++) bfr[n] = *(const bf16x8*)(shm + 4096 + (wc*64 + n*16 + l15)*32 + l4*8);
      #pragma unroll
      for (int m=0;m<4;m++)
        #pragma unroll
        for (int n=0;n<4;n++)
          acc[m][n] = mfma16(af[m], bfr[n], acc[m][n]);
    }
    const int row0 = bm*128 + wr*64;
    const int col0 = bn*128 + wc*64;
    float bvv[4];
    #pragma unroll
    for (int n=0;n<4;n++) bvv[n] = bo[col0 + n*16 + l15];
    #pragma unroll
    for (int m=0;m<4;m++)
      #pragma unroll
      for (int j=0;j<4;j++){
        size_t rb = (size_t)(row0 + m*16 + l4*4 + j)*768 + col0 + l15;
        #pragma unroll
        for (int n=0;n<4;n++) resid[rb + n*16] = acc[m][n][j] + bvv[n] + srcf[rb + n*16];
      }
  } else if (id < 768){
    const int id2 = id - 192;
    const int z = id2 / 288;
    const int rest = id2 - z*288;
    const int koff = z * 1536;
    const int bid = (rest & 7)*36 + (rest >> 3);
    const int bm = bid / 6, bn = bid % 6;
    f32x4 acc[4][4] = {};
    const short* Ag = win_b + (size_t)(bm*128 + wave*32 + (lane>>2))*3072 + (lane&3)*8 + koff;
    const short* Bg = wfc1T + (size_t)(bn*128 + wave*32 + (lane>>2))*3072 + (lane&3)*8 + koff;
    for (int k0 = 0; k0 < 1536; k0 += 32){
      __syncthreads();
      gload16(Ag + k0,           lA);
      gload16(Ag + k0 + 16*3072, lA + 512);
      gload16(Bg + k0,           lB);
      gload16(Bg + k0 + 16*3072, lB + 512);
      __syncthreads();
      bf16x8 af[4], bfr[4];
      #pragma unroll
      for (int m=0;m<4;m++) af[m]  = *(const bf16x8*)(shm + (wr*64 + m*16 + l15)*32 + l4*8);
      #pragma unroll
      for (int n=0;n<4;n++) bfr[n] = *(const bf16x8*)(shm + 4096 + (wc*64 + n*16 + l15)*32 + l4*8);
      #pragma unroll
      for (int m=0;m<4;m++)
        #pragma unroll
        for (int n=0;n<4;n++)
          acc[m][n] = mfma16(af[m], bfr[n], acc[m][n]);
    }
    short* Pz = Pw + (size_t)z * 4718592;
    const int row0 = bm*128 + wr*64;
    const int col0 = bn*128 + wc*64;
    #pragma unroll
    for (int m=0;m<4;m++)
      #pragma unroll
      for (int j=0;j<4;j++){
        size_t rb = (size_t)(row0 + m*16 + l4*4 + j)*768 + col0 + l15;
        #pragma unroll
        for (int n=0;n<4;n++) Pz[rb + n*16] = f2bf(acc[m][n][j]);
      }
  } else {
    int row = (id - 768)*4 + wave;
    const short* wrow = win_b + (size_t)row*3072 + lane*48;
    const float* bb = bfc1 + lane*48;
    float s = 0.f;
    #pragma unroll
    for (int i=0;i<6;i++){
      bf16x8 w = *(const bf16x8*)(wrow + i*8);
      float4 b0 = *(const float4*)(bb + i*8);
      float4 b1 = *(const float4*)(bb + i*8 + 4);
      s += bf2f(w[0])*b0.x + bf2f(w[1])*b0.y + bf2f(w[2])*b0.z + bf2f(w[3])*b0.w
         + bf2f(w[4])*b1.x + bf2f(w[5])*b1.y + bf2f(w[6])*b1.z + bf2f(w[7])*b1.w;
    }
    #pragma unroll
    for (int d=32; d>0; d>>=1) s += __shfl_xor(s, d);
    if (lane == 0) bvg[row] = s;
  }
}

// ---------------- FAT C: rmsnorm2(1024) + wred(4608) ----------------
__global__ void k_fatC(const float* __restrict__ resid, const float* __restrict__ gffn,
                       short* __restrict__ yb,
                       const short* __restrict__ Pw, short* __restrict__ comp){
  const int id = blockIdx.x;
  if (id < 1024){
    int row = id*4 + (threadIdx.x>>6);
    int lane = threadIdx.x & 63;
    const float* xr = resid + (size_t)row*768;
    float4 v[3];
    float ss = 0.f;
    #pragma unroll
    for (int i=0;i<3;i++){
      v[i] = *(const float4*)(xr + i*256 + lane*4);
      ss += v[i].x*v[i].x + v[i].y*v[i].y + v[i].z*v[i].z + v[i].w*v[i].w;
    }
    #pragma unroll
    for (int d=32; d>0; d>>=1) ss += __shfl_xor(ss, d);
    float sc = rsqrtf(ss*(1.f/768.f) + 1.1920929e-7f);
    #pragma unroll
    for (int i=0;i<3;i++){
      int c0 = i*256 + lane*4;
      float4 gv = *(const float4*)(gffn + c0);
      short4v o;
      o.x = f2bf(v[i].x*sc*gv.x); o.y = f2bf(v[i].y*sc*gv.y);
      o.z = f2bf(v[i].z*sc*gv.z); o.w = f2bf(v[i].w*sc*gv.w);
      *(short4v*)(yb + (size_t)row*768 + c0) = o;
    }
  } else {
    int i = (id - 1024)*256 + threadIdx.x;
    short4v a = ((const short4v*)Pw)[i];
    short4v b = ((const short4v*)(Pw + 4718592))[i];
    short4v o;
    o.x = f2bf(bf2f(a.x) + bf2f(b.x)); o.y = f2bf(bf2f(a.y) + bf2f(b.y));
    o.z = f2bf(bf2f(a.z) + bf2f(b.z)); o.w = f2bf(bf2f(a.w) + bf2f(b.w));
    ((short4v*)comp)[i] = o;
  }
}

// ---------------- fc2 split-K partial GEMM: bf16 partials ----------------
__launch_bounds__(256, 2)
__global__ void k_part(const short* __restrict__ Aptr, const short* __restrict__ Bptr,
                       short* __restrict__ Pa, short* __restrict__ Pb){
  __shared__ short ldsA[128*32];
  __shared__ short ldsB[128*32];
  const int t = threadIdx.x;
  const int wave = t >> 6, lane = t & 63;
  const int l15 = lane & 15, l4 = lane >> 4;
  const int K = 3072;
  const int z = blockIdx.z;
  const int koff = z * 768;
  const int bid0 = blockIdx.y * 6 + blockIdx.x;
  const int bid = (bid0 & 7) * 24 + (bid0 >> 3);
  const int bm = bid / 6, bn = bid % 6;
  const int wr = wave >> 1, wc = wave & 1;

  f32x4 acc[4][4] = {};

  const short* Ag = Aptr + (size_t)(bm*128 + wave*32 + (lane>>2))*K + (lane&3)*8 + koff;
  const short* Bg = Bptr + (size_t)(bn*128 + wave*32 + (lane>>2))*K + (lane&3)*8 + koff;
  short* lA = ldsA + wave*1024;
  short* lB = ldsB + wave*1024;

  for (int k0 = 0; k0 < 768; k0 += 32){
    __syncthreads();
    gload16(Ag + k0,                lA);
    gload16(Ag + k0 + 16*(size_t)K, lA + 512);
    gload16(Bg + k0,                lB);
    gload16(Bg + k0 + 16*(size_t)K, lB + 512);
    __syncthreads();
    bf16x8 af[4], bfr[4];
    #pragma unroll
    for (int m=0;m<4;m++) af[m]  = *(const bf16x8*)(ldsA + (wr*64 + m*16 + l15)*32 + l4*8);
    #pragma unroll
    for (int n=0;n<4;n++) bfr[n] = *(const bf16x8*)(ldsB + (wc*64 + n*16 + l15)*32 + l4*8);
    #pragma unroll
    for (int m=0;m<4;m++)
      #pragma unroll
      for (int n=0;n<4;n++)
        acc[m][n] = mfma16(af[m], bfr[n], acc[m][n]);
  }

  short* P = (z < 2) ? (Pa + (size_t)z*3145728) : (Pb + (size_t)(z-2)*3145728);
  const int row0 = bm*128 + wr*64;
  const int col0 = bn*128 + wc*64;
  #pragma unroll
  for (int m=0;m<4;m++)
    #pragma unroll
    for (int j=0;j<4;j++){
      size_t rb = (size_t)(row0 + m*16 + l4*4 + j)*768 + col0 + l15;
      #pragma unroll
      for (int n=0;n<4;n++) P[rb + n*16] = f2bf(acc[m][n][j]);
    }
}

// ---------------- fc2 reduce ----------------
__global__ void k_fc2red(const short* __restrict__ Pa, const short* __restrict__ Pb,
                         const float* __restrict__ bias, const short* __restrict__ yv,
                         float* __restrict__ out){
  int i = blockIdx.x * 256 + threadIdx.x;
  short4v a = ((const short4v*)Pa)[i];
  short4v b = ((const short4v*)(Pa + 3145728))[i];
  short4v c = ((const short4v*)Pb)[i];
  short4v d = ((const short4v*)(Pb + 3145728))[i];
  float4 bv = *(const float4*)(bias + (i % 192)*4);
  short4v y = ((const short4v*)yv)[i];
  float4 o;
  o.x = bf2f(a.x) + bf2f(b.x) + bf2f(c.x) + bf2f(d.x) + bv.x + bf2f(y.x);
  o.y = bf2f(a.y) + bf2f(b.y) + bf2f(c.y) + bf2f(d.y) + bv.y + bf2f(y.y);
  o.z = bf2f(a.z) + bf2f(b.z) + bf2f(c.z) + bf2f(d.z) + bv.z + bf2f(y.z);
  o.w = bf2f(a.w) + bf2f(b.w) + bf2f(c.w) + bf2f(d.w) + bv.w + bf2f(y.w);
  ((float4*)out)[i] = o;
}

// ---------------- Fused SwiGLU GEMM (K=768 composite weights) ----------------
__launch_bounds__(256, 2)
__global__ void k_ffglu(const short* __restrict__ Aptr, const short* __restrict__ Wcomp,
                        const float* __restrict__ bvg, short* __restrict__ Cout){
  __shared__ short lds[3*12288];
  const int tid = threadIdx.x;
  const int wave = tid >> 6, lane = tid & 63;
  const int l15 = lane & 15, l4 = lane >> 4;
  const int wm = wave >> 1, wn = wave & 1;
  const int K = 768, N = 3072;
  const int nt = 24;

  const int lin = blockIdx.y * 48 + blockIdx.x;
  const int xcd = lin & 7, idx = lin >> 3;
  const int bm = ((xcd & 1) << 3) + idx / 12;
  const int bn = (xcd >> 1) * 12 + idx % 12;

  const int srcC = ((lane & 3) ^ ((lane >> 3) & 3)) * 8;

  const short* aSrc[4];
  int aDst[4];
  #pragma unroll
  for (int i=0;i<4;i++){
    int s = i*4 + wave;
    int row = s*16 + (lane>>2);
    aSrc[i] = Aptr + (size_t)(bm*256 + row)*K + srcC;
    aDst[i] = s*512;
  }
  const short* bSrc[2];
  int bDst[2];
  #pragma unroll
  for (int i=0;i<2;i++){
    int j = i*4 + wave;
    int pidx = (j>>1)*16 + (lane>>2);
    int grow = (j & 1) ? 3072 : 0;
    bSrc[i] = Wcomp + (size_t)(grow + bn*64 + pidx)*K + srcC;
    bDst[i] = 8192 + j*512;
  }

  int offA[8], offB[4];
  #pragma unroll
  for (int m=0;m<8;m++){
    int r = wm*128 + m*16 + l15;
    offA[m] = r*32 + ((l4 ^ ((l15>>1)&3))<<3);
  }
  #pragma unroll
  for (int nf=0;nf<4;nf++){
    int r = wn*64 + nf*16 + l15;
    offB[nf] = 8192 + r*32 + ((l4 ^ ((l15>>1)&3))<<3);
  }

  f32x4 accv[8][2] = {};
  f32x4 accg[8][2] = {};

  short *b0 = lds, *b1 = lds + 12288, *b2 = lds + 24576;

  #define GSTAGE_ALL(buf, t) do{ \
    gload16(aSrc[0] + (size_t)(t)*32, (buf) + aDst[0]); \
    gload16(aSrc[1] + (size_t)(t)*32, (buf) + aDst[1]); \
    gload16(aSrc[2] + (size_t)(t)*32, (buf) + aDst[2]); \
    gload16(aSrc[3] + (size_t)(t)*32, (buf) + aDst[3]); \
    gload16(bSrc[0] + (size_t)(t)*32, (buf) + bDst[0]); \
    gload16(bSrc[1] + (size_t)(t)*32, (buf) + bDst[1]); \
  }while(0)

  GSTAGE_ALL(b0, 0);
  GSTAGE_ALL(b1, 1);

  for (int t = 0; t < nt; ++t){
    if (t < nt-1){
      asm volatile("s_waitcnt vmcnt(6)" ::: "memory");
    } else {
      asm volatile("s_waitcnt vmcnt(0)" ::: "memory");
    }
    __builtin_amdgcn_sched_barrier(0);
    __builtin_amdgcn_s_barrier();
    __builtin_amdgcn_sched_barrier(0);

    if (t + 2 < nt) GSTAGE_ALL(b2, t+2);

    bf16x8 a0 = *(const bf16x8*)(b0 + offA[0]);
    bf16x8 a1 = *(const bf16x8*)(b0 + offA[1]);
    bf16x8 a2 = *(const bf16x8*)(b0 + offA[2]);
    bf16x8 a3 = *(const bf16x8*)(b0 + offA[3]);
    bf16x8 a4 = *(const bf16x8*)(b0 + offA[4]);
    bf16x8 a5 = *(const bf16x8*)(b0 + offA[5]);
    bf16x8 a6 = *(const bf16x8*)(b0 + offA[6]);
    bf16x8 a7 = *(const bf16x8*)(b0 + offA[7]);
    bf16x8 v0 = *(const bf16x8*)(b0 + offB[0]);
    bf16x8 g0 = *(const bf16x8*)(b0 + offB[1]);
    bf16x8 v1 = *(const bf16x8*)(b0 + offB[2]);
    bf16x8 g1 = *(const bf16x8*)(b0 + offB[3]);

    __builtin_amdgcn_s_setprio(1);
    accv[0][0] = mfma16(a0, v0, accv[0][0]);  accg[0][0] = mfma16(a0, g0, accg[0][0]);
    accv[1][0] = mfma16(a1, v0, accv[1][0]);  accg[1][0] = mfma16(a1, g0, accg[1][0]);
    accv[2][0] = mfma16(a2, v0, accv[2][0]);  accg[2][0] = mfma16(a2, g0, accg[2][0]);
    accv[3][0] = mfma16(a3, v0, accv[3][0]);  accg[3][0] = mfma16(a3, g0, accg[3][0]);
    accv[0][1] = mfma16(a0, v1, accv[0][1]);  accg[0][1] = mfma16(a0, g1, accg[0][1]);
    accv[1][1] = mfma16(a1, v1, accv[1][1]);  accg[1][1] = mfma16(a1, g1, accg[1][1]);
    accv[2][1] = mfma16(a2, v1, accv[2][1]);  accg[2][1] = mfma16(a2, g1, accg[2][1]);
    accv[3][1] = mfma16(a3, v1, accv[3][1]);  accg[3][1] = mfma16(a3, g1, accg[3][1]);
    accv[4][0] = mfma16(a4, v0, accv[4][0]);  accg[4][0] = mfma16(a4, g0, accg[4][0]);
    accv[5][0] = mfma16(a5, v0, accv[5][0]);  accg[5][0] = mfma16(a5, g0, accg[5][0]);
    accv[6][0] = mfma16(a6, v0, accv[6][0]);  accg[6][0] = mfma16(a6, g0, accg[6][0]);
    accv[7][0] = mfma16(a7, v0, accv[7][0]);  accg[7][0] = mfma16(a7, g0, accg[7][0]);
    accv[4][1] = mfma16(a4, v1, accv[4][1]);  accg[4][1] = mfma16(a4, g1, accg[4][1]);
    accv[5][1] = mfma16(a5, v1, accv[5][1]);  accg[5][1] = mfma16(a5, g1, accg[5][1]);
    accv[6][1] = mfma16(a6, v1, accv[6][1]);  accg[6][1] = mfma16(a6, g1, accg[6][1]);
    accv[7][1] = mfma16(a7, v1, accv[7][1]);  accg[7][1] = mfma16(a7, g1, accg[7][1]);
    __builtin_amdgcn_s_setprio(0);

    short* tmp = b0; b0 = b1; b1 = b2; b2 = tmp;
  }
  #undef GSTAGE_ALL

  const int row0 = bm*256 + wm*128;
  #pragma unroll
  for (int m=0;m<8;m++){
    #pragma unroll
    for (int j=0;j<4;j++){
      size_t rb = (size_t)(row0 + m*16 + l4*4 + j)*N + bn*64 + wn*32 + l15;
      #pragma unroll
      for (int p=0;p<2;p++){
        int c = bn*64 + wn*32 + p*16 + l15;
        float g = accg[m][p][j] + bvg[3072 + c];
        float v = accv[m][p][j] + bvg[c];
        Cout[rb + p*16] = f2bf(v * g / (1.f + __expf(-g)));
      }
    }
  }
}

extern "C" void kernel_launch(void* const* d_in, const int* in_sizes, int n_in,
                              void* d_out, int out_size, void* d_ws, size_t ws_size,
                              hipStream_t stream){
  (void)in_sizes; (void)n_in; (void)out_size;
  const float* src   = (const float*)d_in[0];
  const float* wq    = (const float*)d_in[1];
  const float* bq    = (const float*)d_in[2];
  const float* wk    = (const float*)d_in[3];
  const float* bk    = (const float*)d_in[4];
  const float* wv    = (const float*)d_in[5];
  const float* bv    = (const float*)d_in[6];
  const float* wo    = (const float*)d_in[7];
  const float* bo    = (const float*)d_in[8];
  const float* wfc1  = (const float*)d_in[9];
  const float* bfc1  = (const float*)d_in[10];
  const float* win   = (const float*)d_in[11];
  const float* wgate = (const float*)d_in[12];
  const float* wfc2  = (const float*)d_in[13];
  const float* bfc2  = (const float*)d_in[14];
  const float* gattn = (const float*)d_in[15];
  const float* gffn  = (const float*)d_in[16];

  char* ws = (char*)d_ws;
  constexpr size_t SZ_W768  = 768ull*768*2;
  constexpr size_t SZ_WFC   = 3072ull*768*2;
  constexpr size_t SZ_WFF   = 3072ull*3072*2;
  constexpr size_t SZ_ACT   = 4096ull*768*2;
  constexpr size_t SZ_ACTF  = 4096ull*768*4;
  constexpr size_t SZ_H     = 4096ull*3072*2;
  constexpr size_t OFF_WQ    = 0;
  constexpr size_t OFF_WK    = OFF_WQ + SZ_W768;
  constexpr size_t OFF_WV    = OFF_WK + SZ_W768;
  constexpr size_t OFF_WO    = OFF_WV + SZ_W768;
  constexpr size_t OFF_WFC1  = OFF_WO + SZ_W768;      // gap
  constexpr size_t OFF_WIN   = OFF_WFC1 + SZ_WFC;
  constexpr size_t OFF_WGATE = OFF_WIN + SZ_WFF;
  constexpr size_t OFF_WFC2  = OFF_WGATE + SZ_WFF;
  constexpr size_t OFF_XN    = OFF_WFC2 + SZ_WFC;
  constexpr size_t OFF_Q     = OFF_XN + SZ_ACT;
  constexpr size_t OFF_K     = OFF_Q + SZ_ACT;
  constexpr size_t OFF_V     = OFF_K + SZ_ACT;
  constexpr size_t OFF_RES   = OFF_V + SZ_ACT;
  constexpr size_t OFF_HIN   = OFF_RES + SZ_ACTF;
  constexpr size_t OFF_H2    = OFF_HIN + SZ_H;
  constexpr size_t WS_NEED   = OFF_H2 + SZ_H;
  if (ws_size < WS_NEED) return;

  constexpr size_t OFF_COMP  = OFF_HIN;                       // [6144 x 768] bf16
  constexpr size_t OFF_T     = OFF_HIN + 6144ull*768*2;       // wfc1T
  constexpr size_t OFF_BVG   = OFF_T + 768ull*3072*2;         // f32[6144]

  short* wq_b    = (short*)(ws+OFF_WQ);      // [wq;wk;wv] contiguous = QKV weight, then wo
  short* win_b   = (short*)(ws+OFF_WIN);     // [win;wgate;wfc2] contiguous dst
  short* wfc2_b  = (short*)(ws+OFF_WFC2);
  short* wo_b    = (short*)(ws+OFF_WO);
  short* xn      = (short*)(ws+OFF_XN);
  short* ctxb    = (short*)(ws+OFF_XN);
  short* qb      = (short*)(ws+OFF_Q);
  short* yb      = (short*)(ws+OFF_Q);
  short* kb2     = (short*)(ws+OFF_K);
  short* vb2     = (short*)(ws+OFF_V);
  float* resid   = (float*)(ws+OFF_RES);
  short* comp    = (short*)(ws+OFF_COMP);
  short* wfc1T   = (short*)(ws+OFF_T);
  float* bvg     = (float*)(ws+OFF_BVG);
  short* h2      = (short*)(ws+OFF_H2);
  short* Pw      = (short*)(ws+OFF_H2);      // wcomp bf16 partials (dead before ffglu writes h2)
  short* partA   = (short*)(ws+OFF_HIN);     // fc2 bf16 partials (after comp consumed)
  short* partB   = (short*)(ws+OFF_K);

  // 1. FAT D: small weight convert (wq..wo) || rmsnorm1
  k_fatD<<<3328, 256, 0, stream>>>(wq, wk, wv, wo, wq_b, src, gattn, xn);

  // 2. QKV projection: pipelined 256x64 structure (+rope, V^T packed stores)
  k_qkv<<<dim3(36,16), 256, 0, stream>>>(xn, wq_b, bq, bk, bv, qb, kb2, vb2);

  // 3. FAT A: attention || convert big weights || transpose-convert wfc1
  k_fatA<<<23808, 256, 0, stream>>>(qb, kb2, vb2, ctxb, win, wgate, wfc2, win_b, wfc1, wfc1T);

  // 4. FAT B: Wo projection (+residual) || wcomp split-K partials || composite bias gemv
  k_fatB<<<2304, 256, 0, stream>>>(ctxb, wo_b, resid, bo, src, win_b, wfc1T, Pw, bfc1, bvg);

  // 5. FAT C: rmsnorm2 || wcomp reduce
  k_fatC<<<5632, 256, 0, stream>>>(resid, gffn, yb, Pw, comp);

  // 6. fused SwiGLU with composite weights (K=768)
  k_ffglu<<<dim3(48,16), 256, 0, stream>>>(yb, comp, bvg, h2);

  // 7. fc2 split-K=4 (bf16 partials) + fused reduce -> d_out
  k_part<<<dim3(6,32,4), 256, 0, stream>>>(h2, wfc2_b, partA, partB);
  k_fc2red<<<3072, 256, 0, stream>>>(partA, partB, bfc2, yb, (float*)d_out);
}

// Round 20
// 232.292 us; speedup vs baseline: 1.0410x; 1.0410x over previous
//
#include <hip/hip_runtime.h>

#define DEV static __device__ __forceinline__

typedef __attribute__((ext_vector_type(8))) short bf16x8;
typedef __attribute__((ext_vector_type(4))) short short4v;
typedef __attribute__((ext_vector_type(4))) float f32x4;

DEV f32x4 mfma16(bf16x8 a, bf16x8 b, f32x4 c){
  return __builtin_amdgcn_mfma_f32_16x16x32_bf16(a, b, c, 0, 0, 0);
}
DEV float bf2f(short s){ union{unsigned u; float f;} v; v.u=((unsigned)(unsigned short)s)<<16; return v.f; }
DEV short f2bf(float f){ union{float f; unsigned u;} v; v.f=f; unsigned r=v.u+0x7fffu+((v.u>>16)&1u); return (short)(r>>16); }
DEV void gload16(const void* g, void* l){
  __builtin_amdgcn_global_load_lds((const __attribute__((address_space(1))) void*)g,
                                   (__attribute__((address_space(3))) void*)l, 16, 0, 0);
}
DEV int cvtpk(float lo, float hi){
  int r; asm("v_cvt_pk_bf16_f32 %0, %1, %2" : "=v"(r) : "v"(lo), "v"(hi)); return r;
}

enum { EPI_QKV=4 };

// ---------------- FAT D: convert wq..wo (2304) || rmsnorm1 (1024) ----------------
__global__ void k_fatD(const float* __restrict__ p0, const float* __restrict__ p1,
                       const float* __restrict__ p2, const float* __restrict__ p3,
                       short* __restrict__ dst,
                       const float* __restrict__ x, const float* __restrict__ g,
                       short* __restrict__ out){
  const int id = blockIdx.x;
  const int tid = threadIdx.x;
  if (id < 2304){
    int v = id*256 + tid;
    const float* src; int rel;
    if      (v < 147456){ src=p0; rel=v; }
    else if (v < 294912){ src=p1; rel=v-147456; }
    else if (v < 442368){ src=p2; rel=v-294912; }
    else                { src=p3; rel=v-442368; }
    float4 xv = ((const float4*)src)[rel];
    short4v o; o.x=f2bf(xv.x); o.y=f2bf(xv.y); o.z=f2bf(xv.z); o.w=f2bf(xv.w);
    ((short4v*)dst)[v] = o;
  } else {
    int row = (id-2304)*4 + (tid>>6);
    int lane = tid & 63;
    const float* xr = x + (size_t)row*768;
    float4 v[3];
    float ss = 0.f;
    #pragma unroll
    for (int i=0;i<3;i++){
      v[i] = *(const float4*)(xr + i*256 + lane*4);
      ss += v[i].x*v[i].x + v[i].y*v[i].y + v[i].z*v[i].z + v[i].w*v[i].w;
    }
    #pragma unroll
    for (int d=32; d>0; d>>=1) ss += __shfl_xor(ss, d);
    float sc = rsqrtf(ss*(1.f/768.f) + 1.1920929e-7f);
    #pragma unroll
    for (int i=0;i<3;i++){
      int c0 = i*256 + lane*4;
      float4 gv = *(const float4*)(g + c0);
      short4v o;
      o.x = f2bf(v[i].x*sc*gv.x); o.y = f2bf(v[i].y*sc*gv.y);
      o.z = f2bf(v[i].z*sc*gv.z); o.w = f2bf(v[i].w*sc*gv.w);
      *(short4v*)(out + (size_t)row*768 + c0) = o;
    }
  }
}

// ---------------- NT GEMM (m97): QKV (N=2304), 3 blocks/CU ----------------
template<int EPI>
__launch_bounds__(256, 3)
__global__ void k_gemm(const short* __restrict__ Aptr, const short* __restrict__ Bptr,
                       void* __restrict__ Cout, const float* __restrict__ bias,
                       const void* __restrict__ aux, const float* __restrict__ bias2,
                       const float* __restrict__ bias3, const void* __restrict__ aux2,
                       int M, int N, int K){
  __shared__ short ldsA[128*32];
  __shared__ short ldsB[128*32];
  const int t = threadIdx.x;
  const int wave = t >> 6, lane = t & 63;
  const int l15 = lane & 15, l4 = lane >> 4;
  const int nwg = gridDim.x * gridDim.y;
  const int bid0 = blockIdx.y * gridDim.x + blockIdx.x;
  const int cpx = nwg >> 3;
  const int bid = (bid0 & 7) * cpx + (bid0 >> 3);
  const int bm = bid / gridDim.x, bn = bid % gridDim.x;
  const int wr = wave >> 1, wc = wave & 1;

  f32x4 acc[4][4] = {};

  const short* Ag = Aptr + (size_t)(bm*128 + wave*32 + (lane>>2))*K + (lane&3)*8;
  const short* Bg = Bptr + (size_t)(bn*128 + wave*32 + (lane>>2))*K + (lane&3)*8;
  short* lA = ldsA + wave*1024;
  short* lB = ldsB + wave*1024;

  for (int k0 = 0; k0 < K; k0 += 32){
    __syncthreads();
    gload16(Ag + k0,                lA);
    gload16(Ag + k0 + 16*(size_t)K, lA + 512);
    gload16(Bg + k0,                lB);
    gload16(Bg + k0 + 16*(size_t)K, lB + 512);
    __syncthreads();
    bf16x8 af[4], bfr[4];
    #pragma unroll
    for (int m=0;m<4;m++) af[m]  = *(const bf16x8*)(ldsA + (wr*64 + m*16 + l15)*32 + l4*8);
    #pragma unroll
    for (int n=0;n<4;n++) bfr[n] = *(const bf16x8*)(ldsB + (wc*64 + n*16 + l15)*32 + l4*8);
    #pragma unroll
    for (int m=0;m<4;m++)
      #pragma unroll
      for (int n=0;n<4;n++)
        acc[m][n] = mfma16(af[m], bfr[n], acc[m][n]);
  }

  const int row0 = bm*128 + wr*64;
  const int col0 = bn*128 + wc*64;

  if constexpr (EPI == EPI_QKV){
    const int proj = col0 / 768;
    const int c768 = col0 - proj*768;
    const int h = c768 >> 6;
    const float* bs = proj==0 ? bias : (proj==1 ? bias2 : bias3);
    float bvv[4];
    #pragma unroll
    for (int n=0;n<4;n++) bvv[n] = bs[c768 + n*16 + l15];
    if (proj == 2){
      short* Ov = (short*)const_cast<void*>(aux2);
      #pragma unroll
      for (int m=0;m<4;m++){
        int s0 = row0 + m*16 + l4*4;
        int b = s0 >> 11, s = s0 & 2047;
        size_t hb = (size_t)(b*12 + h)*64;
        #pragma unroll
        for (int n=0;n<4;n++){
          short4v pk;
          pk.x = f2bf(acc[m][n][0] + bvv[n]);
          pk.y = f2bf(acc[m][n][1] + bvv[n]);
          pk.z = f2bf(acc[m][n][2] + bvv[n]);
          pk.w = f2bf(acc[m][n][3] + bvv[n]);
          *(short4v*)(Ov + (hb + n*16 + l15)*2048 + s) = pk;
        }
      }
    } else {
      short* O = proj==0 ? (short*)Cout : (short*)const_cast<void*>(aux);
      const float sc = proj==0 ? 0.18033688011112042f : 1.0f;   // 0.125*log2(e)
      const float RC = 0.41524101186092034f;  // log2(10000)/32
      float invf0 = exp2f(-(float)l15 * RC);
      float invf1 = exp2f(-(float)(16 + l15) * RC);
      #pragma unroll
      for (int m=0;m<4;m++){
        #pragma unroll
        for (int j=0;j<4;j++){
          int row = row0 + m*16 + l4*4 + j;
          int b = row >> 11, s = row & 2047;
          size_t obase = ((size_t)(b*12 + h)*2048 + (size_t)s)*64;
          float a0 = acc[m][0][j] + bvv[0];
          float a1 = acc[m][1][j] + bvv[1];
          float a2 = acc[m][2][j] + bvv[2];
          float a3 = acc[m][3][j] + bvv[3];
          float sn0, cs0, sn1, cs1;
          __sincosf((float)s * invf0, &sn0, &cs0);
          __sincosf((float)s * invf1, &sn1, &cs1);
          O[obase + l15]      = f2bf((a0*cs0 - a2*sn0)*sc);
          O[obase + 16 + l15] = f2bf((a1*cs1 - a3*sn1)*sc);
          O[obase + 32 + l15] = f2bf((a2*cs0 + a0*sn0)*sc);
          O[obase + 48 + l15] = f2bf((a3*cs1 + a1*sn1)*sc);
        }
      }
    }
  }
}

// ---------------- FAT A: attn(768) + convert win/wgate/wfc2 (20736) + convertT (2304) ----------------
__launch_bounds__(256, 5)
__global__ void k_fatA(const short* __restrict__ Q, const short* __restrict__ Kb,
                       const short* __restrict__ Vb, short* __restrict__ ctx,
                       const float* __restrict__ winf, const float* __restrict__ wgf,
                       const float* __restrict__ wfc2f, short* __restrict__ dstbig,
                       const float* __restrict__ wfc1, short* __restrict__ wfc1T){
  __shared__ short shm[16384];   // attn: K dbuf [0,8192), V dbuf [8192,16384)
  const int id = blockIdx.x;
  const int tid = threadIdx.x;

  if (id < 768){
    const int wave = tid>>6, lane = tid&63;
    const int l15 = lane&15, l4 = lane>>4;
    const int qt = id & 31, bh = id >> 5;
    const short* Qh  = Q  + (size_t)bh*2048*64;
    const short* Kh  = Kb + (size_t)bh*2048*64;
    const short* Vth = Vb + (size_t)bh*64*2048;

    const int r7  = lane>>3;
    const int swz = ((lane&7) ^ r7) << 3;
    const int rr0 = wave*8 + r7, rr1 = 32 + wave*8 + r7;
    const size_t kOff0 = (size_t)rr0*64   + swz, kOff1 = (size_t)rr1*64   + swz;
    const size_t vOff0 = (size_t)rr0*2048 + swz, vOff1 = (size_t)rr1*2048 + swz;

    bf16x8 qf[2];
    #pragma unroll
    for (int kf=0;kf<2;kf++)
      qf[kf] = *(const bf16x8*)(Qh + (size_t)(qt*64 + wave*16 + l15)*64 + kf*32 + l4*8);

    f32x4 cacc[4] = {};
    f32x4 lacc = {};
    union { int w[4]; bf16x8 v; } onesf;
    onesf.w[0] = onesf.w[1] = onesf.w[2] = onesf.w[3] = 0x3F803F80;

    #define STAGE(sel, kv0) do { \
      const short* ksp = Kh + (size_t)(kv0)*64; \
      const short* vsp = Vth + (kv0); \
      short* kd = shm + (sel)*4096 + wave*512; \
      short* vd = shm + 8192 + (sel)*4096 + wave*512; \
      gload16(ksp + kOff0, kd); \
      gload16(ksp + kOff1, kd + 2048); \
      gload16(vsp + vOff0, vd); \
      gload16(vsp + vOff1, vd + 2048); \
    } while(0)

    STAGE(0, 0);

    for (int tt = 0; tt < 32; ++tt){
      const int cur = tt & 1;
      if (tt < 31){
        STAGE(cur^1, (tt+1)*64);
        asm volatile("s_waitcnt vmcnt(4)" ::: "memory");
      } else {
        asm volatile("s_waitcnt vmcnt(0)" ::: "memory");
      }
      __builtin_amdgcn_sched_barrier(0);
      __builtin_amdgcn_s_barrier();
      __builtin_amdgcn_sched_barrier(0);

      const short* KtC = shm + cur*4096;
      const short* VtC = shm + 8192 + cur*4096;

      f32x4 sacc[4] = {};
      __builtin_amdgcn_s_setprio(1);
      #pragma unroll
      for (int kf=0;kf<2;kf++){
        #pragma unroll
        for (int mk=0;mk<4;mk++){
          int r = mk*16 + l15;
          bf16x8 kfr = *(const bf16x8*)(KtC + r*64 + (((kf*4+l4) ^ (l15&7))<<3));
          sacc[mk] = mfma16(kfr, qf[kf], sacc[mk]);
        }
      }
      __builtin_amdgcn_s_setprio(0);

      int pk01[4], pk23[4];
      #pragma unroll
      for (int mk=0;mk<4;mk++){
        float p0 = exp2f(sacc[mk][0]);
        float p1 = exp2f(sacc[mk][1]);
        float p2 = exp2f(sacc[mk][2]);
        float p3 = exp2f(sacc[mk][3]);
        pk01[mk] = cvtpk(p0, p1);
        pk23[mk] = cvtpk(p2, p3);
      }

      #pragma unroll
      for (int ks=0;ks<2;ks++){
        int srcA = l15 + ((l4&1)<<5);
        int srcB = srcA + 16;
        int hi = l4>>1;
        int w0a = __shfl(pk01[2*ks], srcA), w0b = __shfl(pk01[2*ks+1], srcA);
        int w1a = __shfl(pk23[2*ks], srcA), w1b = __shfl(pk23[2*ks+1], srcA);
        int w2a = __shfl(pk01[2*ks], srcB), w2b = __shfl(pk01[2*ks+1], srcB);
        int w3a = __shfl(pk23[2*ks], srcB), w3b = __shfl(pk23[2*ks+1], srcB);
        union { int w[4]; bf16x8 v; } pa;
        pa.w[0] = hi ? w0b : w0a;
        pa.w[1] = hi ? w1b : w1a;
        pa.w[2] = hi ? w2b : w2a;
        pa.w[3] = hi ? w3b : w3a;
        __builtin_amdgcn_s_setprio(1);
        #pragma unroll
        for (int nf=0;nf<4;nf++){
          int dh = nf*16 + l15;
          bf16x8 vf = *(const bf16x8*)(VtC + dh*64 + (((ks*4+l4) ^ (dh&7))<<3));
          cacc[nf] = mfma16(pa.v, vf, cacc[nf]);
        }
        lacc = mfma16(pa.v, onesf.v, lacc);
        __builtin_amdgcn_s_setprio(0);
      }

      __builtin_amdgcn_sched_barrier(0);
      __builtin_amdgcn_s_barrier();
    }
    #undef STAGE

    const int b = bh/12, h = bh%12;
    #pragma unroll
    for (int j=0;j<4;j++){
      float inv = 1.f / lacc[j];
      int s = qt*64 + wave*16 + l4*4 + j;
      size_t base = ((size_t)b*2048 + s)*768 + h*64;
      #pragma unroll
      for (int nf=0;nf<4;nf++)
        ctx[base + nf*16 + l15] = f2bf(cacc[nf][j] * inv);
    }
  } else if (id < 21504){
    int v = (id - 768)*256 + tid;
    const float* src; int rel;
    if      (v < 2359296){ src=winf;  rel=v; }
    else if (v < 4718592){ src=wgf;   rel=v-2359296; }
    else                 { src=wfc2f; rel=v-4718592; }
    float4 x = ((const float4*)src)[rel];
    short4v o; o.x=f2bf(x.x); o.y=f2bf(x.y); o.z=f2bf(x.z); o.w=f2bf(x.w);
    ((short4v*)dstbig)[v] = o;
  } else {
    int idx = id - 21504;
    int f0 = (idx % 96)*32, d0 = (idx / 96)*32;
    float* lt = (float*)shm;     // [32][33]
    int r = tid >> 3, c4 = tid & 7;
    float4 v = *(const float4*)(wfc1 + (size_t)(f0 + r)*768 + d0 + c4*4);
    lt[r*33 + c4*4+0] = v.x; lt[r*33 + c4*4+1] = v.y;
    lt[r*33 + c4*4+2] = v.z; lt[r*33 + c4*4+3] = v.w;
    __syncthreads();
    short4v o;
    o.x = f2bf(lt[(c4*4+0)*33 + r]);
    o.y = f2bf(lt[(c4*4+1)*33 + r]);
    o.z = f2bf(lt[(c4*4+2)*33 + r]);
    o.w = f2bf(lt[(c4*4+3)*33 + r]);
    *(short4v*)(wfc1T + (size_t)(d0 + r)*3072 + f0 + c4*4) = o;
  }
}

// ---------------- FAT B: Wo-RESID(192) + wpart(576) + gemv(1536), 3 blocks/CU ----------------
__launch_bounds__(256, 3)
__global__ void k_fatB(const short* __restrict__ ctxb, const short* __restrict__ wo_b,
                       float* __restrict__ resid, const float* __restrict__ bo,
                       const float* __restrict__ srcf,
                       const short* __restrict__ win_b, const short* __restrict__ wfc1T,
                       short* __restrict__ Pw,
                       const float* __restrict__ bfc1, float* __restrict__ bvg){
  __shared__ short shm[8192];
  const int id = blockIdx.x;
  const int t = threadIdx.x;
  const int wave = t >> 6, lane = t & 63;
  const int l15 = lane & 15, l4 = lane >> 4;
  const int wr = wave >> 1, wc = wave & 1;
  short* lA = shm + wave*1024;
  short* lB = shm + 4096 + wave*1024;

  if (id < 192){
    const int bid = (id & 7)*24 + (id >> 3);
    const int bm = bid / 6, bn = bid % 6;
    f32x4 acc[4][4] = {};
    const short* Ag = ctxb + (size_t)(bm*128 + wave*32 + (lane>>2))*768 + (lane&3)*8;
    const short* Bg = wo_b + (size_t)(bn*128 + wave*32 + (lane>>2))*768 + (lane&3)*8;
    for (int k0 = 0; k0 < 768; k0 += 32){
      __syncthreads();
      gload16(Ag + k0,          lA);
      gload16(Ag + k0 + 16*768, lA + 512);
      gload16(Bg + k0,          lB);
      gload16(Bg + k0 + 16*768, lB + 512);
      __syncthreads();
      bf16x8 af[4], bfr[4];
      #pragma unroll
      for (int m=0;m<4;m++) af[m]  = *(const bf16x8*)(shm + (wr*64 + m*16 + l15)*32 + l4*8);
      #pragma unroll
      for (int n=0;n<4;n++) bfr[n] = *(const bf16x8*)(shm + 4096 + (wc*64 + n*16 + l15)*32 + l4*8);
      #pragma unroll
      for (int m=0;m<4;m++)
        #pragma unroll
        for (int n=0;n<4;n++)
          acc[m][n] = mfma16(af[m], bfr[n], acc[m][n]);
    }
    const int row0 = bm*128 + wr*64;
    const int col0 = bn*128 + wc*64;
    float bvv[4];
    #pragma unroll
    for (int n=0;n<4;n++) bvv[n] = bo[col0 + n*16 + l15];
    #pragma unroll
    for (int m=0;m<4;m++)
      #pragma unroll
      for (int j=0;j<4;j++){
        size_t rb = (size_t)(row0 + m*16 + l4*4 + j)*768 + col0 + l15;
        #pragma unroll
        for (int n=0;n<4;n++) resid[rb + n*16] = acc[m][n][j] + bvv[n] + srcf[rb + n*16];
      }
  } else if (id < 768){
    const int id2 = id - 192;
    const int z = id2 / 288;
    const int rest = id2 - z*288;
    const int koff = z * 1536;
    const int bid = (rest & 7)*36 + (rest >> 3);
    const int bm = bid / 6, bn = bid % 6;
    f32x4 acc[4][4] = {};
    const short* Ag = win_b + (size_t)(bm*128 + wave*32 + (lane>>2))*3072 + (lane&3)*8 + koff;
    const short* Bg = wfc1T + (size_t)(bn*128 + wave*32 + (lane>>2))*3072 + (lane&3)*8 + koff;
    for (int k0 = 0; k0 < 1536; k0 += 32){
      __syncthreads();
      gload16(Ag + k0,           lA);
      gload16(Ag + k0 + 16*3072, lA + 512);
      gload16(Bg + k0,           lB);
      gload16(Bg + k0 + 16*3072, lB + 512);
      __syncthreads();
      bf16x8 af[4], bfr[4];
      #pragma unroll
      for (int m=0;m<4;m++) af[m]  = *(const bf16x8*)(shm + (wr*64 + m*16 + l15)*32 + l4*8);
      #pragma unroll
      for (int n=0;n<4;n++) bfr[n] = *(const bf16x8*)(shm + 4096 + (wc*64 + n*16 + l15)*32 + l4*8);
      #pragma unroll
      for (int m=0;m<4;m++)
        #pragma unroll
        for (int n=0;n<4;n++)
          acc[m][n] = mfma16(af[m], bfr[n], acc[m][n]);
    }
    short* Pz = Pw + (size_t)z * 4718592;
    const int row0 = bm*128 + wr*64;
    const int col0 = bn*128 + wc*64;
    #pragma unroll
    for (int m=0;m<4;m++)
      #pragma unroll
      for (int j=0;j<4;j++){
        size_t rb = (size_t)(row0 + m*16 + l4*4 + j)*768 + col0 + l15;
        #pragma unroll
        for (int n=0;n<4;n++) Pz[rb + n*16] = f2bf(acc[m][n][j]);
      }
  } else {
    int row = (id - 768)*4 + wave;
    const short* wrow = win_b + (size_t)row*3072 + lane*48;
    const float* bb = bfc1 + lane*48;
    float s = 0.f;
    #pragma unroll
    for (int i=0;i<6;i++){
      bf16x8 w = *(const bf16x8*)(wrow + i*8);
      float4 b0 = *(const float4*)(bb + i*8);
      float4 b1 = *(const float4*)(bb + i*8 + 4);
      s += bf2f(w[0])*b0.x + bf2f(w[1])*b0.y + bf2f(w[2])*b0.z + bf2f(w[3])*b0.w
         + bf2f(w[4])*b1.x + bf2f(w[5])*b1.y + bf2f(w[6])*b1.z + bf2f(w[7])*b1.w;
    }
    #pragma unroll
    for (int d=32; d>0; d>>=1) s += __shfl_xor(s, d);
    if (lane == 0) bvg[row] = s;
  }
}

// ---------------- FAT C: rmsnorm2(1024) + wred(4608) ----------------
__global__ void k_fatC(const float* __restrict__ resid, const float* __restrict__ gffn,
                       short* __restrict__ yb,
                       const short* __restrict__ Pw, short* __restrict__ comp){
  const int id = blockIdx.x;
  if (id < 1024){
    int row = id*4 + (threadIdx.x>>6);
    int lane = threadIdx.x & 63;
    const float* xr = resid + (size_t)row*768;
    float4 v[3];
    float ss = 0.f;
    #pragma unroll
    for (int i=0;i<3;i++){
      v[i] = *(const float4*)(xr + i*256 + lane*4);
      ss += v[i].x*v[i].x + v[i].y*v[i].y + v[i].z*v[i].z + v[i].w*v[i].w;
    }
    #pragma unroll
    for (int d=32; d>0; d>>=1) ss += __shfl_xor(ss, d);
    float sc = rsqrtf(ss*(1.f/768.f) + 1.1920929e-7f);
    #pragma unroll
    for (int i=0;i<3;i++){
      int c0 = i*256 + lane*4;
      float4 gv = *(const float4*)(gffn + c0);
      short4v o;
      o.x = f2bf(v[i].x*sc*gv.x); o.y = f2bf(v[i].y*sc*gv.y);
      o.z = f2bf(v[i].z*sc*gv.z); o.w = f2bf(v[i].w*sc*gv.w);
      *(short4v*)(yb + (size_t)row*768 + c0) = o;
    }
  } else {
    int i = (id - 1024)*256 + threadIdx.x;
    short4v a = ((const short4v*)Pw)[i];
    short4v b = ((const short4v*)(Pw + 4718592))[i];
    short4v o;
    o.x = f2bf(bf2f(a.x) + bf2f(b.x)); o.y = f2bf(bf2f(a.y) + bf2f(b.y));
    o.z = f2bf(bf2f(a.z) + bf2f(b.z)); o.w = f2bf(bf2f(a.w) + bf2f(b.w));
    ((short4v*)comp)[i] = o;
  }
}

// ---------------- fc2 split-K partial GEMM: bf16 partials, 3 blocks/CU ----------------
__launch_bounds__(256, 3)
__global__ void k_part(const short* __restrict__ Aptr, const short* __restrict__ Bptr,
                       short* __restrict__ Pa, short* __restrict__ Pb){
  __shared__ short ldsA[128*32];
  __shared__ short ldsB[128*32];
  const int t = threadIdx.x;
  const int wave = t >> 6, lane = t & 63;
  const int l15 = lane & 15, l4 = lane >> 4;
  const int K = 3072;
  const int z = blockIdx.z;
  const int koff = z * 768;
  const int bid0 = blockIdx.y * 6 + blockIdx.x;
  const int bid = (bid0 & 7) * 24 + (bid0 >> 3);
  const int bm = bid / 6, bn = bid % 6;
  const int wr = wave >> 1, wc = wave & 1;

  f32x4 acc[4][4] = {};

  const short* Ag = Aptr + (size_t)(bm*128 + wave*32 + (lane>>2))*K + (lane&3)*8 + koff;
  const short* Bg = Bptr + (size_t)(bn*128 + wave*32 + (lane>>2))*K + (lane&3)*8 + koff;
  short* lA = ldsA + wave*1024;
  short* lB = ldsB + wave*1024;

  for (int k0 = 0; k0 < 768; k0 += 32){
    __syncthreads();
    gload16(Ag + k0,                lA);
    gload16(Ag + k0 + 16*(size_t)K, lA + 512);
    gload16(Bg + k0,                lB);
    gload16(Bg + k0 + 16*(size_t)K, lB + 512);
    __syncthreads();
    bf16x8 af[4], bfr[4];
    #pragma unroll
    for (int m=0;m<4;m++) af[m]  = *(const bf16x8*)(ldsA + (wr*64 + m*16 + l15)*32 + l4*8);
    #pragma unroll
    for (int n=0;n<4;n++) bfr[n] = *(const bf16x8*)(ldsB + (wc*64 + n*16 + l15)*32 + l4*8);
    #pragma unroll
    for (int m=0;m<4;m++)
      #pragma unroll
      for (int n=0;n<4;n++)
        acc[m][n] = mfma16(af[m], bfr[n], acc[m][n]);
  }

  short* P = (z < 2) ? (Pa + (size_t)z*3145728) : (Pb + (size_t)(z-2)*3145728);
  const int row0 = bm*128 + wr*64;
  const int col0 = bn*128 + wc*64;
  #pragma unroll
  for (int m=0;m<4;m++)
    #pragma unroll
    for (int j=0;j<4;j++){
      size_t rb = (size_t)(row0 + m*16 + l4*4 + j)*768 + col0 + l15;
      #pragma unroll
      for (int n=0;n<4;n++) P[rb + n*16] = f2bf(acc[m][n][j]);
    }
}

// ---------------- fc2 reduce ----------------
__global__ void k_fc2red(const short* __restrict__ Pa, const short* __restrict__ Pb,
                         const float* __restrict__ bias, const short* __restrict__ yv,
                         float* __restrict__ out){
  int i = blockIdx.x * 256 + threadIdx.x;
  short4v a = ((const short4v*)Pa)[i];
  short4v b = ((const short4v*)(Pa + 3145728))[i];
  short4v c = ((const short4v*)Pb)[i];
  short4v d = ((const short4v*)(Pb + 3145728))[i];
  float4 bv = *(const float4*)(bias + (i % 192)*4);
  short4v y = ((const short4v*)yv)[i];
  float4 o;
  o.x = bf2f(a.x) + bf2f(b.x) + bf2f(c.x) + bf2f(d.x) + bv.x + bf2f(y.x);
  o.y = bf2f(a.y) + bf2f(b.y) + bf2f(c.y) + bf2f(d.y) + bv.y + bf2f(y.y);
  o.z = bf2f(a.z) + bf2f(b.z) + bf2f(c.z) + bf2f(d.z) + bv.z + bf2f(y.z);
  o.w = bf2f(a.w) + bf2f(b.w) + bf2f(c.w) + bf2f(d.w) + bv.w + bf2f(y.w);
  ((float4*)out)[i] = o;
}

// ---------------- Fused SwiGLU GEMM (K=768 composite weights) ----------------
__launch_bounds__(256, 2)
__global__ void k_ffglu(const short* __restrict__ Aptr, const short* __restrict__ Wcomp,
                        const float* __restrict__ bvg, short* __restrict__ Cout){
  __shared__ short lds[3*12288];
  const int tid = threadIdx.x;
  const int wave = tid >> 6, lane = tid & 63;
  const int l15 = lane & 15, l4 = lane >> 4;
  const int wm = wave >> 1, wn = wave & 1;
  const int K = 768, N = 3072;
  const int nt = 24;

  const int lin = blockIdx.y * 48 + blockIdx.x;
  const int xcd = lin & 7, idx = lin >> 3;
  const int bm = ((xcd & 1) << 3) + idx / 12;
  const int bn = (xcd >> 1) * 12 + idx % 12;

  const int srcC = ((lane & 3) ^ ((lane >> 3) & 3)) * 8;

  const short* aSrc[4];
  int aDst[4];
  #pragma unroll
  for (int i=0;i<4;i++){
    int s = i*4 + wave;
    int row = s*16 + (lane>>2);
    aSrc[i] = Aptr + (size_t)(bm*256 + row)*K + srcC;
    aDst[i] = s*512;
  }
  const short* bSrc[2];
  int bDst[2];
  #pragma unroll
  for (int i=0;i<2;i++){
    int j = i*4 + wave;
    int pidx = (j>>1)*16 + (lane>>2);
    int grow = (j & 1) ? 3072 : 0;
    bSrc[i] = Wcomp + (size_t)(grow + bn*64 + pidx)*K + srcC;
    bDst[i] = 8192 + j*512;
  }

  int offA[8], offB[4];
  #pragma unroll
  for (int m=0;m<8;m++){
    int r = wm*128 + m*16 + l15;
    offA[m] = r*32 + ((l4 ^ ((l15>>1)&3))<<3);
  }
  #pragma unroll
  for (int nf=0;nf<4;nf++){
    int r = wn*64 + nf*16 + l15;
    offB[nf] = 8192 + r*32 + ((l4 ^ ((l15>>1)&3))<<3);
  }

  f32x4 accv[8][2] = {};
  f32x4 accg[8][2] = {};

  short *b0 = lds, *b1 = lds + 12288, *b2 = lds + 24576;

  #define GSTAGE_ALL(buf, t) do{ \
    gload16(aSrc[0] + (size_t)(t)*32, (buf) + aDst[0]); \
    gload16(aSrc[1] + (size_t)(t)*32, (buf) + aDst[1]); \
    gload16(aSrc[2] + (size_t)(t)*32, (buf) + aDst[2]); \
    gload16(aSrc[3] + (size_t)(t)*32, (buf) + aDst[3]); \
    gload16(bSrc[0] + (size_t)(t)*32, (buf) + bDst[0]); \
    gload16(bSrc[1] + (size_t)(t)*32, (buf) + bDst[1]); \
  }while(0)

  GSTAGE_ALL(b0, 0);
  GSTAGE_ALL(b1, 1);

  for (int t = 0; t < nt; ++t){
    if (t < nt-1){
      asm volatile("s_waitcnt vmcnt(6)" ::: "memory");
    } else {
      asm volatile("s_waitcnt vmcnt(0)" ::: "memory");
    }
    __builtin_amdgcn_sched_barrier(0);
    __builtin_amdgcn_s_barrier();
    __builtin_amdgcn_sched_barrier(0);

    if (t + 2 < nt) GSTAGE_ALL(b2, t+2);

    bf16x8 a0 = *(const bf16x8*)(b0 + offA[0]);
    bf16x8 a1 = *(const bf16x8*)(b0 + offA[1]);
    bf16x8 a2 = *(const bf16x8*)(b0 + offA[2]);
    bf16x8 a3 = *(const bf16x8*)(b0 + offA[3]);
    bf16x8 a4 = *(const bf16x8*)(b0 + offA[4]);
    bf16x8 a5 = *(const bf16x8*)(b0 + offA[5]);
    bf16x8 a6 = *(const bf16x8*)(b0 + offA[6]);
    bf16x8 a7 = *(const bf16x8*)(b0 + offA[7]);
    bf16x8 v0 = *(const bf16x8*)(b0 + offB[0]);
    bf16x8 g0 = *(const bf16x8*)(b0 + offB[1]);
    bf16x8 v1 = *(const bf16x8*)(b0 + offB[2]);
    bf16x8 g1 = *(const bf16x8*)(b0 + offB[3]);

    __builtin_amdgcn_s_setprio(1);
    accv[0][0] = mfma16(a0, v0, accv[0][0]);  accg[0][0] = mfma16(a0, g0, accg[0][0]);
    accv[1][0] = mfma16(a1, v0, accv[1][0]);  accg[1][0] = mfma16(a1, g0, accg[1][0]);
    accv[2][0] = mfma16(a2, v0, accv[2][0]);  accg[2][0] = mfma16(a2, g0, accg[2][0]);
    accv[3][0] = mfma16(a3, v0, accv[3][0]);  accg[3][0] = mfma16(a3, g0, accg[3][0]);
    accv[0][1] = mfma16(a0, v1, accv[0][1]);  accg[0][1] = mfma16(a0, g1, accg[0][1]);
    accv[1][1] = mfma16(a1, v1, accv[1][1]);  accg[1][1] = mfma16(a1, g1, accg[1][1]);
    accv[2][1] = mfma16(a2, v1, accv[2][1]);  accg[2][1] = mfma16(a2, g1, accg[2][1]);
    accv[3][1] = mfma16(a3, v1, accv[3][1]);  accg[3][1] = mfma16(a3, g1, accg[3][1]);
    accv[4][0] = mfma16(a4, v0, accv[4][0]);  accg[4][0] = mfma16(a4, g0, accg[4][0]);
    accv[5][0] = mfma16(a5, v0, accv[5][0]);  accg[5][0] = mfma16(a5, g0, accg[5][0]);
    accv[6][0] = mfma16(a6, v0, accv[6][0]);  accg[6][0] = mfma16(a6, g0, accg[6][0]);
    accv[7][0] = mfma16(a7, v0, accv[7][0]);  accg[7][0] = mfma16(a7, g0, accg[7][0]);
    accv[4][1] = mfma16(a4, v1, accv[4][1]);  accg[4][1] = mfma16(a4, g1, accg[4][1]);
    accv[5][1] = mfma16(a5, v1, accv[5][1]);  accg[5][1] = mfma16(a5, g1, accg[5][1]);
    accv[6][1] = mfma16(a6, v1, accv[6][1]);  accg[6][1] = mfma16(a6, g1, accg[6][1]);
    accv[7][1] = mfma16(a7, v1, accv[7][1]);  accg[7][1] = mfma16(a7, g1, accg[7][1]);
    __builtin_amdgcn_s_setprio(0);

    short* tmp = b0; b0 = b1; b1 = b2; b2 = tmp;
  }
  #undef GSTAGE_ALL

  const int row0 = bm*256 + wm*128;
  #pragma unroll
  for (int m=0;m<8;m++){
    #pragma unroll
    for (int j=0;j<4;j++){
      size_t rb = (size_t)(row0 + m*16 + l4*4 + j)*N + bn*64 + wn*32 + l15;
      #pragma unroll
      for (int p=0;p<2;p++){
        int c = bn*64 + wn*32 + p*16 + l15;
        float g = accg[m][p][j] + bvg[3072 + c];
        float v = accv[m][p][j] + bvg[c];
        Cout[rb + p*16] = f2bf(v * g / (1.f + __expf(-g)));
      }
    }
  }
}

extern "C" void kernel_launch(void* const* d_in, const int* in_sizes, int n_in,
                              void* d_out, int out_size, void* d_ws, size_t ws_size,
                              hipStream_t stream){
  (void)in_sizes; (void)n_in; (void)out_size;
  const float* src   = (const float*)d_in[0];
  const float* wq    = (const float*)d_in[1];
  const float* bq    = (const float*)d_in[2];
  const float* wk    = (const float*)d_in[3];
  const float* bk    = (const float*)d_in[4];
  const float* wv    = (const float*)d_in[5];
  const float* bv    = (const float*)d_in[6];
  const float* wo    = (const float*)d_in[7];
  const float* bo    = (const float*)d_in[8];
  const float* wfc1  = (const float*)d_in[9];
  const float* bfc1  = (const float*)d_in[10];
  const float* win   = (const float*)d_in[11];
  const float* wgate = (const float*)d_in[12];
  const float* wfc2  = (const float*)d_in[13];
  const float* bfc2  = (const float*)d_in[14];
  const float* gattn = (const float*)d_in[15];
  const float* gffn  = (const float*)d_in[16];

  char* ws = (char*)d_ws;
  constexpr size_t SZ_W768  = 768ull*768*2;
  constexpr size_t SZ_WFC   = 3072ull*768*2;
  constexpr size_t SZ_WFF   = 3072ull*3072*2;
  constexpr size_t SZ_ACT   = 4096ull*768*2;
  constexpr size_t SZ_ACTF  = 4096ull*768*4;
  constexpr size_t SZ_H     = 4096ull*3072*2;
  constexpr size_t OFF_WQ    = 0;
  constexpr size_t OFF_WK    = OFF_WQ + SZ_W768;
  constexpr size_t OFF_WV    = OFF_WK + SZ_W768;
  constexpr size_t OFF_WO    = OFF_WV + SZ_W768;
  constexpr size_t OFF_WFC1  = OFF_WO + SZ_W768;      // gap
  constexpr size_t OFF_WIN   = OFF_WFC1 + SZ_WFC;
  constexpr size_t OFF_WGATE = OFF_WIN + SZ_WFF;
  constexpr size_t OFF_WFC2  = OFF_WGATE + SZ_WFF;
  constexpr size_t OFF_XN    = OFF_WFC2 + SZ_WFC;
  constexpr size_t OFF_Q     = OFF_XN + SZ_ACT;
  constexpr size_t OFF_K     = OFF_Q + SZ_ACT;
  constexpr size_t OFF_V     = OFF_K + SZ_ACT;
  constexpr size_t OFF_RES   = OFF_V + SZ_ACT;
  constexpr size_t OFF_HIN   = OFF_RES + SZ_ACTF;
  constexpr size_t OFF_H2    = OFF_HIN + SZ_H;
  constexpr size_t WS_NEED   = OFF_H2 + SZ_H;
  if (ws_size < WS_NEED) return;

  constexpr size_t OFF_COMP  = OFF_HIN;                       // [6144 x 768] bf16
  constexpr size_t OFF_T     = OFF_HIN + 6144ull*768*2;       // wfc1T
  constexpr size_t OFF_BVG   = OFF_T + 768ull*3072*2;         // f32[6144]

  short* wq_b    = (short*)(ws+OFF_WQ);
  short* win_b   = (short*)(ws+OFF_WIN);
  short* wfc2_b  = (short*)(ws+OFF_WFC2);
  short* wo_b    = (short*)(ws+OFF_WO);
  short* xn      = (short*)(ws+OFF_XN);
  short* ctxb    = (short*)(ws+OFF_XN);
  short* qb      = (short*)(ws+OFF_Q);
  short* yb      = (short*)(ws+OFF_Q);
  short* kb2     = (short*)(ws+OFF_K);
  short* vb2     = (short*)(ws+OFF_V);
  float* resid   = (float*)(ws+OFF_RES);
  short* comp    = (short*)(ws+OFF_COMP);
  short* wfc1T   = (short*)(ws+OFF_T);
  float* bvg     = (float*)(ws+OFF_BVG);
  short* h2      = (short*)(ws+OFF_H2);
  short* Pw      = (short*)(ws+OFF_H2);
  short* partA   = (short*)(ws+OFF_HIN);
  short* partB   = (short*)(ws+OFF_K);

  // 1. FAT D: small weight convert (wq..wo) || rmsnorm1
  k_fatD<<<3328, 256, 0, stream>>>(wq, wk, wv, wo, wq_b, src, gattn, xn);

  // 2. QKV projection (+rope, V^T packed stores)
  k_gemm<EPI_QKV><<<dim3(18,32), 256, 0, stream>>>(xn, wq_b, qb, bq, kb2, bk, bv, vb2, 4096, 2304, 768);

  // 3. FAT A: attention || convert big weights || transpose-convert wfc1
  k_fatA<<<23808, 256, 0, stream>>>(qb, kb2, vb2, ctxb, win, wgate, wfc2, win_b, wfc1, wfc1T);

  // 4. FAT B: Wo projection (+residual) || wcomp split-K partials || composite bias gemv
  k_fatB<<<2304, 256, 0, stream>>>(ctxb, wo_b, resid, bo, src, win_b, wfc1T, Pw, bfc1, bvg);

  // 5. FAT C: rmsnorm2 || wcomp reduce
  k_fatC<<<5632, 256, 0, stream>>>(resid, gffn, yb, Pw, comp);

  // 6. fused SwiGLU with composite weights (K=768)
  k_ffglu<<<dim3(48,16), 256, 0, stream>>>(yb, comp, bvg, h2);

  // 7. fc2 split-K=4 (bf16 partials) + fused reduce -> d_out
  k_part<<<dim3(6,32,4), 256, 0, stream>>>(h2, wfc2_b, partA, partB);
  k_fc2red<<<3072, 256, 0, stream>>>(partA, partB, bfc2, yb, (float*)d_out);
}